// Round 1
// baseline (2334.538 us; speedup 1.0000x reference)
//
#include <hip/hip_runtime.h>
#include <cstdint>
#include <cstddef>

#define B_ 2
#define D_ 4096
#define S_ 2048
#define F_ 16384

typedef __attribute__((ext_vector_type(8))) short bf16x8;
typedef __attribute__((ext_vector_type(4))) float f32x4;

__device__ __forceinline__ unsigned short f2bf(float f) {
  union { float f; unsigned int u; } c; c.f = f;
  unsigned int u = c.u + 0x7fffu + ((c.u >> 16) & 1u);
  return (unsigned short)(u >> 16);
}

// ---------------- convert fp32 -> bf16 (vectorized) ----------------
__global__ void cvt_kernel(const float4* __restrict__ src, ushort4* __restrict__ dst, int n4) {
  int i = blockIdx.x * blockDim.x + threadIdx.x;
  if (i >= n4) return;
  float4 v = src[i];
  ushort4 o;
  o.x = f2bf(v.x); o.y = f2bf(v.y); o.z = f2bf(v.z); o.w = f2bf(v.w);
  dst[i] = o;
}

// ---------------- transpose-cast x (B,D,S) f32 -> xt (B,S,D) bf16 ----------------
__global__ void transpose_cast_kernel(const float* __restrict__ x, unsigned short* __restrict__ xt) {
  __shared__ float t[32][33];
  int b = blockIdx.z;
  int d0 = blockIdx.y * 32, s0 = blockIdx.x * 32;
  const float* xb = x + (size_t)b * D_ * S_;
  unsigned short* xtb = xt + (size_t)b * S_ * D_;
  int tx = threadIdx.x;   // 0..31
  int ty = threadIdx.y;   // 0..7
#pragma unroll
  for (int r = 0; r < 4; ++r)
    t[ty + r * 8][tx] = xb[(size_t)(d0 + ty + r * 8) * S_ + s0 + tx];
  __syncthreads();
#pragma unroll
  for (int r = 0; r < 4; ++r)
    xtb[(size_t)(s0 + ty + r * 8) * D_ + d0 + tx] = f2bf(t[tx][ty + r * 8]);
}

// ---------------- GEMM helpers ----------------
// Tile: 128 rows x 64 cols bf16, flat 16 KiB in LDS, stored as 16B granules.
// granule (m, kbs) in LDS holds global granule (m, kbs ^ (m&7))  [XOR swizzle,
// makes ds_read_b128 fragment reads ~conflict-free without padding, which
// global_load_lds (uniform base + lane*16) cannot support].
__device__ __forceinline__ void stage_tile_128x64(const unsigned short* g, int ld,
                                                  unsigned short* lds, int tid) {
#pragma unroll
  for (int c = 0; c < 4; ++c) {
    int gran = c * 256 + tid;            // 0..1023
    int m = gran >> 3;                   // row 0..127
    int kb = (gran & 7) ^ (m & 7);       // source granule within row
    const unsigned short* gp = g + m * ld + kb * 8;
    __builtin_amdgcn_global_load_lds(
        (const __attribute__((address_space(1))) unsigned int*)gp,
        (__attribute__((address_space(3))) unsigned int*)(lds + gran * 8),
        16, 0, 0);
  }
}

__device__ __forceinline__ bf16x8 frag_load(const unsigned short* tile, int row, int kb) {
  int off = (row * 8 + (kb ^ (row & 7))) * 8;
  return *(const bf16x8*)(tile + off);
}

// ---------------- fused dual GEMM1 + gelu*up, writes ht (B,S,F) bf16 ----------------
// C tile: M=f (128), N=s (128). 4 waves in 2x2, each 64x64 (4x4 of 16x16x32 MFMA).
__launch_bounds__(256, 2)
__global__ void ffn_gemm1(const unsigned short* __restrict__ w0b,
                          const unsigned short* __restrict__ w1b,
                          const unsigned short* __restrict__ xt,
                          unsigned short* __restrict__ ht) {
  __shared__ __align__(16) unsigned short sh[3 * 8192];  // 48 KiB
  unsigned short* As0 = sh;
  unsigned short* As1 = sh + 8192;
  unsigned short* Bs  = sh + 16384;

  const int tid = threadIdx.x;
  const int b = blockIdx.z;
  const int f0 = blockIdx.y * 128;
  const int s0 = blockIdx.x * 128;

  const unsigned short* a0g = w0b + (size_t)f0 * D_;
  const unsigned short* a1g = w1b + (size_t)f0 * D_;
  const unsigned short* bg  = xt + (size_t)b * S_ * D_ + (size_t)s0 * D_;

  const int lane = tid & 63;
  const int wid = tid >> 6;
  const int wm = (wid >> 1) * 64;
  const int wn = (wid & 1) * 64;
  const int lr = lane & 15;
  const int kq = lane >> 4;  // 0..3

  f32x4 accg[4][4] = {};
  f32x4 accu[4][4] = {};

  for (int k0 = 0; k0 < D_; k0 += 64) {
    stage_tile_128x64(a0g + k0, D_, As0, tid);
    stage_tile_128x64(a1g + k0, D_, As1, tid);
    stage_tile_128x64(bg + k0, D_, Bs, tid);
    __syncthreads();
#pragma unroll
    for (int kk = 0; kk < 2; ++kk) {
      const int kb = kk * 4 + kq;
      bf16x8 bfr[4];
#pragma unroll
      for (int j = 0; j < 4; ++j)
        bfr[j] = frag_load(Bs, wn + j * 16 + lr, kb);
#pragma unroll
      for (int i = 0; i < 4; ++i) {
        int m = wm + i * 16 + lr;
        bf16x8 a0 = frag_load(As0, m, kb);
        bf16x8 a1 = frag_load(As1, m, kb);
#pragma unroll
        for (int j = 0; j < 4; ++j) {
          accg[i][j] = __builtin_amdgcn_mfma_f32_16x16x32_bf16(a0, bfr[j], accg[i][j], 0, 0, 0);
          accu[i][j] = __builtin_amdgcn_mfma_f32_16x16x32_bf16(a1, bfr[j], accu[i][j], 0, 0, 0);
        }
      }
    }
    __syncthreads();
  }

  // epilogue: h = gelu(g)*u; transpose through LDS so ht is (S,F) with f contiguous
  unsigned short* hl = sh;  // reuse as [128][136] bf16 (34816 B < 48 KiB)
#pragma unroll
  for (int i = 0; i < 4; ++i)
#pragma unroll
    for (int j = 0; j < 4; ++j)
#pragma unroll
      for (int r = 0; r < 4; ++r) {
        float g = accg[i][j][r];
        float u = accu[i][j][r];
        float h = 0.5f * g * (1.0f + erff(g * 0.70710678118654752f)) * u;
        int m = wm + i * 16 + kq * 4 + r;   // f within tile
        int n = wn + j * 16 + lr;           // s within tile
        hl[n * 136 + m] = f2bf(h);
      }
  __syncthreads();
  unsigned short* htb = ht + (size_t)b * S_ * F_ + (size_t)s0 * F_ + f0;
#pragma unroll
  for (int p = 0; p < 8; ++p) {
    int e = p * 2048 + tid * 8;
    int n = e >> 7;
    int f = e & 127;
    uint4 v = *(const uint4*)(hl + n * 136 + f);
    *(uint4*)(htb + (size_t)n * F_ + f) = v;
  }
}

// ---------------- GEMM2: out(B,D,S) f32 = w_out(D,F) @ ht(B,S,F)^T ----------------
__launch_bounds__(256, 2)
__global__ void ffn_gemm2(const unsigned short* __restrict__ woutb,
                          const unsigned short* __restrict__ ht,
                          float* __restrict__ out) {
  __shared__ __align__(16) unsigned short sh[2 * 8192];  // 32 KiB
  unsigned short* As = sh;
  unsigned short* Bs = sh + 8192;

  const int tid = threadIdx.x;
  const int b = blockIdx.z;
  const int d0 = blockIdx.y * 128;
  const int s0 = blockIdx.x * 128;

  const unsigned short* ag = woutb + (size_t)d0 * F_;
  const unsigned short* bg = ht + (size_t)b * S_ * F_ + (size_t)s0 * F_;

  const int lane = tid & 63;
  const int wid = tid >> 6;
  const int wm = (wid >> 1) * 64;
  const int wn = (wid & 1) * 64;
  const int lr = lane & 15;
  const int kq = lane >> 4;

  f32x4 acc[4][4] = {};

  for (int k0 = 0; k0 < F_; k0 += 64) {
    stage_tile_128x64(ag + k0, F_, As, tid);
    stage_tile_128x64(bg + k0, F_, Bs, tid);
    __syncthreads();
#pragma unroll
    for (int kk = 0; kk < 2; ++kk) {
      const int kb = kk * 4 + kq;
      bf16x8 bfr[4];
#pragma unroll
      for (int j = 0; j < 4; ++j)
        bfr[j] = frag_load(Bs, wn + j * 16 + lr, kb);
#pragma unroll
      for (int i = 0; i < 4; ++i) {
        bf16x8 a = frag_load(As, wm + i * 16 + lr, kb);
#pragma unroll
        for (int j = 0; j < 4; ++j)
          acc[i][j] = __builtin_amdgcn_mfma_f32_16x16x32_bf16(a, bfr[j], acc[i][j], 0, 0, 0);
      }
    }
    __syncthreads();
  }

  float* outb = out + (size_t)b * D_ * S_;
#pragma unroll
  for (int i = 0; i < 4; ++i)
#pragma unroll
    for (int j = 0; j < 4; ++j)
#pragma unroll
      for (int r = 0; r < 4; ++r) {
        int m = wm + i * 16 + kq * 4 + r;   // d within tile
        int n = wn + j * 16 + lr;           // s within tile
        outb[(size_t)(d0 + m) * S_ + s0 + n] = acc[i][j][r];
      }
}

// ---------------- launch ----------------
extern "C" void kernel_launch(void* const* d_in, const int* in_sizes, int n_in,
                              void* d_out, int out_size, void* d_ws, size_t ws_size,
                              hipStream_t stream) {
  const float* x     = (const float*)d_in[0];
  const float* w0    = (const float*)d_in[1];
  const float* w1    = (const float*)d_in[2];
  const float* w_out = (const float*)d_in[3];
  float* out = (float*)d_out;

  char* ws = (char*)d_ws;
  // layout (bytes): w0b 128M | w1b 128M | woutb 128M | xt 32M | ht 128M  = 544 MiB
  unsigned short* w0b   = (unsigned short*)(ws);
  unsigned short* w1b   = (unsigned short*)(ws + 134217728UL);
  unsigned short* woutb = (unsigned short*)(ws + 268435456UL);
  unsigned short* xt    = (unsigned short*)(ws + 402653184UL);
  unsigned short* ht    = (unsigned short*)(ws + 436207616UL);

  const int n4 = (F_ * D_) / 4;  // 16,777,216 float4 per weight matrix
  hipLaunchKernelGGL(cvt_kernel, dim3(n4 / 256), dim3(256), 0, stream,
                     (const float4*)w0, (ushort4*)w0b, n4);
  hipLaunchKernelGGL(cvt_kernel, dim3(n4 / 256), dim3(256), 0, stream,
                     (const float4*)w1, (ushort4*)w1b, n4);
  hipLaunchKernelGGL(cvt_kernel, dim3(n4 / 256), dim3(256), 0, stream,
                     (const float4*)w_out, (ushort4*)woutb, n4);
  hipLaunchKernelGGL(transpose_cast_kernel, dim3(S_ / 32, D_ / 32, B_), dim3(32, 8), 0, stream,
                     x, xt);
  hipLaunchKernelGGL(ffn_gemm1, dim3(S_ / 128, F_ / 128, B_), dim3(256), 0, stream,
                     w0b, w1b, xt, ht);
  hipLaunchKernelGGL(ffn_gemm2, dim3(S_ / 128, D_ / 128, B_), dim3(256), 0, stream,
                     woutb, ht, out);
}